// Round 10
// baseline (509.850 us; speedup 1.0000x reference)
//
#include <hip/hip_runtime.h>
#include <stdint.h>

#define NH 12
#define HD64 64
#define SEQ 1025
#define M_ROWS (16 * SEQ)   // 16400
#define DIM 768
#define NPAD 1088           // 17 * 64, keeps V^T rows 16B-aligned

typedef __attribute__((ext_vector_type(8))) short bf16x8;
typedef __attribute__((ext_vector_type(4))) float f32x4;
typedef __attribute__((ext_vector_type(4))) short s16x4;

__device__ __forceinline__ short f2bf_rne(float f) {
    union { float f; uint32_t u; } c; c.f = f;
    uint32_t u = c.u + 0x7fffu + ((c.u >> 16) & 1u);
    return (short)(u >> 16);
}

__device__ __forceinline__ int cvt_pk_bf16(float lo, float hi) {
    int r;
    asm("v_cvt_pk_bf16_f32 %0, %1, %2" : "=v"(r) : "v"(lo), "v"(hi));
    return r;
}

__device__ __forceinline__ void gload_lds16(const void* g, void* l) {
    __builtin_amdgcn_global_load_lds(
        (const __attribute__((address_space(1))) void*)g,
        (__attribute__((address_space(3))) void*)l, 16, 0, 0);
}

// T1: XCD-chunked bijective swizzle (m204).
__device__ __forceinline__ int xcd_chunk_swizzle(int orig, int nwg) {
    int q = nwg >> 3, r = nwg & 7;
    int xcd = orig & 7, i = orig >> 3;
    int start = (xcd < r) ? xcd * (q + 1) : r * (q + 1) + (xcd - r) * q;
    return start + i;
}

// ---------------- fp32 -> bf16 conversion (merged, one launch) ----------------
__global__ void f2bf3_kernel(const float* __restrict__ a, short* __restrict__ ao, int na4,
                             const float* __restrict__ b, short* __restrict__ bo, int nb4,
                             const float* __restrict__ c, short* __restrict__ co, int nc4) {
    int i = blockIdx.x * blockDim.x + threadIdx.x;
    const float* src; short* dst; int idx;
    if (i < na4) { src = a; dst = ao; idx = i; }
    else if (i < na4 + nb4) { src = b; dst = bo; idx = i - na4; }
    else if (i < na4 + nb4 + nc4) { src = c; dst = co; idx = i - na4 - nb4; }
    else return;
    f32x4 f = ((const f32x4*)src)[idx];
    s16x4 o;
    o[0] = f2bf_rne(f[0]); o[1] = f2bf_rne(f[1]);
    o[2] = f2bf_rne(f[2]); o[3] = f2bf_rne(f[3]);
    ((s16x4*)dst)[idx] = o;
}

// ============== direct-from-global GEMM core (no LDS, no barriers) ============
// 4 waves, wave-tile 64x64, block 128x128. Each wave loads its MFMA fragments
// straight from global (L1/L2-resident panels): 8 loop-invariant row pointers,
// fragment = bf16x8 at ptr + kt*64B (imm-offset after full unroll). 8 loads +
// 16 MFMA per K-step, zero sync -> compiler pipelines loads across steps,
// 12 waves/CU of TLP absorb latency. Co-resident blocks share the A panel
// (consecutive swizzled tiles have equal mt) -> L1 reuse.

// ---------------- QKV GEMM + RoPE epilogue ----------------
__global__ __launch_bounds__(256) void qkv_gemm_kernel(
    const short* __restrict__ xb, const short* __restrict__ wb,
    const float* __restrict__ fcos, const float* __restrict__ fsin,
    short* __restrict__ Qb, short* __restrict__ Kb, short* __restrict__ VTb)
{
    const int tid = threadIdx.x;
    const int lane = tid & 63, w = tid >> 6;
    const int wm = w >> 1, wn = w & 1;
    const int lr = lane & 15, lg = lane >> 4;
    const int tile = xcd_chunk_swizzle(blockIdx.x, 129 * 18);
    const int mt = tile / 18, nt = tile - (tile / 18) * 18;

    const short* pA[4];
    const short* pB[4];
#pragma unroll
    for (int mi = 0; mi < 4; mi++) {
        int r = mt * 128 + wm * 64 + mi * 16 + lr;
        if (r > M_ROWS - 1) r = M_ROWS - 1;
        pA[mi] = xb + (size_t)r * DIM + lg * 8;
    }
#pragma unroll
    for (int ni = 0; ni < 4; ni++) {
        int e = nt * 128 + wn * 64 + ni * 16 + lr;   // < 2304 always
        pB[ni] = wb + (size_t)e * DIM + lg * 8;
    }

    f32x4 acc[4][4];
#pragma unroll
    for (int i = 0; i < 4; i++)
#pragma unroll
        for (int j = 0; j < 4; j++) acc[i][j] = (f32x4)0.0f;

#pragma unroll
    for (int kt = 0; kt < 24; ++kt) {
        bf16x8 af[4], bfr[4];
#pragma unroll
        for (int mi = 0; mi < 4; mi++)
            af[mi] = *(const bf16x8*)(pA[mi] + kt * 32);
#pragma unroll
        for (int ni = 0; ni < 4; ni++)
            bfr[ni] = *(const bf16x8*)(pB[ni] + kt * 32);
#pragma unroll
        for (int mi = 0; mi < 4; mi++)
#pragma unroll
            for (int ni = 0; ni < 4; ni++)
                acc[mi][ni] = __builtin_amdgcn_mfma_f32_16x16x32_bf16(af[mi], bfr[ni], acc[mi][ni], 0, 0, 0);
    }

    // epilogue: RoPE (pairs are adjacent cols = lane^1), scale Q, scatter
#pragma unroll
    for (int mi = 0; mi < 4; mi++) {
        int mbase = mt * 128 + wm * 64 + mi * 16 + lg * 4;
#pragma unroll
        for (int j = 0; j < 4; j++) {
            int m = mbase + j;
            bool valid = (m < M_ROWS);
            int mm = valid ? m : 0;
            int b = mm / SEQ;
            int n = mm - b * SEQ;
#pragma unroll
            for (int ni = 0; ni < 4; ni++) {
                int e = nt * 128 + wn * 64 + ni * 16 + lr;
                int qkv = e / DIM;
                int rem = e - qkv * DIM;
                int h = rem >> 6, d = rem & 63;
                float v = acc[mi][ni][j];
                float vo = __shfl_xor(v, 1);       // partner col e^1 (uniform exec)
                float outv = v;
                if (qkv < 2 && n > 0) {
                    float cs = fcos[(n - 1) * 32 + (d >> 1)];
                    float sn = fsin[(n - 1) * 32 + (d >> 1)];
                    outv = (d & 1) ? (vo * sn + v * cs) : (v * cs - vo * sn);
                }
                if (qkv == 0) outv *= 0.180336881f;   // 1/sqrt(64) * log2(e)
                if (valid) {
                    short bv = f2bf_rne(outv);
                    size_t bh = (size_t)b * NH + h;
                    if (qkv == 0)      Qb[(bh * SEQ + n) * HD64 + d] = bv;
                    else if (qkv == 1) Kb[(bh * SEQ + n) * HD64 + d] = bv;
                    else               VTb[(bh * HD64 + d) * NPAD + n] = bv;
                }
            }
        }
    }
}

// ---------------- output projection GEMM + bias (same direct core) -----------
__global__ __launch_bounds__(256) void proj_gemm_kernel(
    const short* __restrict__ ab, const short* __restrict__ wb,
    const float* __restrict__ bias, float* __restrict__ out)
{
    const int tid = threadIdx.x;
    const int lane = tid & 63, w = tid >> 6;
    const int wm = w >> 1, wn = w & 1;
    const int lr = lane & 15, lg = lane >> 4;
    const int tile = xcd_chunk_swizzle(blockIdx.x, 129 * 6);
    const int mt = tile / 6, nt = tile - (tile / 6) * 6;

    const short* pA[4];
    const short* pB[4];
#pragma unroll
    for (int mi = 0; mi < 4; mi++) {
        int r = mt * 128 + wm * 64 + mi * 16 + lr;
        if (r > M_ROWS - 1) r = M_ROWS - 1;
        pA[mi] = ab + (size_t)r * DIM + lg * 8;
    }
#pragma unroll
    for (int ni = 0; ni < 4; ni++) {
        int e = nt * 128 + wn * 64 + ni * 16 + lr;   // < 768 always
        pB[ni] = wb + (size_t)e * DIM + lg * 8;
    }

    f32x4 acc[4][4];
#pragma unroll
    for (int i = 0; i < 4; i++)
#pragma unroll
        for (int j = 0; j < 4; j++) acc[i][j] = (f32x4)0.0f;

#pragma unroll
    for (int kt = 0; kt < 24; ++kt) {
        bf16x8 af[4], bfr[4];
#pragma unroll
        for (int mi = 0; mi < 4; mi++)
            af[mi] = *(const bf16x8*)(pA[mi] + kt * 32);
#pragma unroll
        for (int ni = 0; ni < 4; ni++)
            bfr[ni] = *(const bf16x8*)(pB[ni] + kt * 32);
#pragma unroll
        for (int mi = 0; mi < 4; mi++)
#pragma unroll
            for (int ni = 0; ni < 4; ni++)
                acc[mi][ni] = __builtin_amdgcn_mfma_f32_16x16x32_bf16(af[mi], bfr[ni], acc[mi][ni], 0, 0, 0);
    }

#pragma unroll
    for (int ni = 0; ni < 4; ni++) {
        int e = nt * 128 + wn * 64 + ni * 16 + lr;
        float bv = bias[e];
#pragma unroll
        for (int mi = 0; mi < 4; mi++) {
#pragma unroll
            for (int j = 0; j < 4; j++) {
                int m = mt * 128 + wm * 64 + mi * 16 + lg * 4 + j;
                if (m < M_ROWS) out[(size_t)m * DIM + e] = acc[mi][ni][j] + bv;
            }
        }
    }
}

// ---------------- flash attention ----------------
// (unchanged: swapped QK^T, in-register softmax, dbuf K/V, T13 defer-max, T5)
__global__ __launch_bounds__(256) void attn_kernel(
    const short* __restrict__ Qb, const short* __restrict__ Kb,
    const short* __restrict__ VTb, short* __restrict__ AO)
{
    __shared__ short Klds[2][64 * 64];
    __shared__ short Vlds[2][64 * 64];
    __shared__ int Plds[4][16 * 32];
    const int tid = threadIdx.x;
    const int lane = tid & 63, w = tid >> 6;
    const int lr = lane & 15, lg = lane >> 4;
    const int tile = xcd_chunk_swizzle(blockIdx.x, 17 * 192);
    const int bh = tile / 17, qt = tile - (tile / 17) * 17;
    const int b = bh / NH, h = bh - b * NH;

    const short* Qp = Qb + (size_t)bh * SEQ * HD64;
    const short* Kp = Kb + (size_t)bh * SEQ * HD64;
    const short* Vp = VTb + (size_t)bh * HD64 * NPAD;

    int qr = qt * 64 + w * 16 + lr; if (qr > SEQ - 1) qr = SEQ - 1;
    bf16x8 qf0 = *(const bf16x8*)&Qp[(size_t)qr * HD64 + 0 + lg * 8];
    bf16x8 qf1 = *(const bf16x8*)&Qp[(size_t)qr * HD64 + 32 + lg * 8];

    float m_i = -1e30f, l_i = 0.f;
    f32x4 acc[4];
#pragma unroll
    for (int vt = 0; vt < 4; vt++) acc[vt] = (f32x4)0.0f;

    int* pw = &Plds[w][0];
    const int pswz = (lr & 3) << 3;

    auto stageKV = [&](int buf, int t) {
        int k0 = t * 64;
#pragma unroll
        for (int i = 0; i < 2; i++) {
            int c = i * 256 + tid;
            int row = c >> 3, ccd = c & 7;
            int cl = ccd ^ (row & 7);
            int krow = k0 + row; if (krow > SEQ - 1) krow = SEQ - 1;
            gload_lds16(Kp + (size_t)krow * HD64 + cl * 8, &Klds[buf][c * 8]);
            gload_lds16(Vp + (size_t)row * NPAD + k0 + cl * 8, &Vlds[buf][c * 8]);
        }
    };

    stageKV(0, 0);
    asm volatile("s_waitcnt vmcnt(0)" ::: "memory");
    __syncthreads();

    for (int t = 0; t < 17; ++t) {
        int cur = t & 1;
        if (t < 16) stageKV(cur ^ 1, t + 1);

        f32x4 s[4];
        __builtin_amdgcn_s_setprio(1);
#pragma unroll
        for (int k16 = 0; k16 < 4; k16++) {
            int krow = k16 * 16 + lr;
            bf16x8 kf0 = *(const bf16x8*)&Klds[cur][krow * 64 + ((0 + lg) ^ (krow & 7)) * 8];
            bf16x8 kf1 = *(const bf16x8*)&Klds[cur][krow * 64 + ((4 + lg) ^ (krow & 7)) * 8];
            f32x4 d = (f32x4)0.0f;
            d = __builtin_amdgcn_mfma_f32_16x16x32_bf16(kf0, qf0, d, 0, 0, 0);
            d = __builtin_amdgcn_mfma_f32_16x16x32_bf16(kf1, qf1, d, 0, 0, 0);
            s[k16] = d;
        }
        __builtin_amdgcn_s_setprio(0);
        if (t == 16) {
            s[0][0] = (lg == 0) ? s[0][0] : -1e30f;
            s[0][1] = -1e30f; s[0][2] = -1e30f; s[0][3] = -1e30f;
#pragma unroll
            for (int k16 = 1; k16 < 4; k16++) { s[k16][0] = -1e30f; s[k16][1] = -1e30f; s[k16][2] = -1e30f; s[k16][3] = -1e30f; }
        }

        float a0 = fmaxf(s[0][0], s[0][1]), a1 = fmaxf(s[0][2], s[0][3]);
        float a2 = fmaxf(s[1][0], s[1][1]), a3 = fmaxf(s[1][2], s[1][3]);
        float a4 = fmaxf(s[2][0], s[2][1]), a5 = fmaxf(s[2][2], s[2][3]);
        float a6 = fmaxf(s[3][0], s[3][1]), a7 = fmaxf(s[3][2], s[3][3]);
        float b0 = fmaxf(fmaxf(a0, a1), fmaxf(a2, a3));
        float b1 = fmaxf(fmaxf(a4, a5), fmaxf(a6, a7));
        float pmax = fmaxf(b0, b1);
        pmax = fmaxf(pmax, __shfl_xor(pmax, 16));
        pmax = fmaxf(pmax, __shfl_xor(pmax, 32));

        if (__any(pmax > m_i + 11.54f)) {
            float mnew = fmaxf(m_i, pmax);
            float sc = exp2f(m_i - mnew);
            m_i = mnew;
            l_i *= sc;
#pragma unroll
            for (int j = 0; j < 4; j++) {
                float scj = __shfl(sc, 4 * lg + j);
#pragma unroll
                for (int vt = 0; vt < 4; vt++) acc[vt][j] *= scj;
            }
        }

#pragma unroll
        for (int k16 = 0; k16 < 4; k16++) {
#pragma unroll
            for (int j = 0; j < 4; j++) s[k16][j] = exp2f(s[k16][j] - m_i);
        }
        float r0 = (s[0][0] + s[0][1]) + (s[0][2] + s[0][3]);
        float r1 = (s[1][0] + s[1][1]) + (s[1][2] + s[1][3]);
        float r2 = (s[2][0] + s[2][1]) + (s[2][2] + s[2][3]);
        float r3 = (s[3][0] + s[3][1]) + (s[3][2] + s[3][3]);
        float rowsum = (r0 + r1) + (r2 + r3);
        rowsum += __shfl_xor(rowsum, 16);
        rowsum += __shfl_xor(rowsum, 32);
        l_i += rowsum;

#pragma unroll
        for (int k16 = 0; k16 < 4; k16++) {
            int pk0 = cvt_pk_bf16(s[k16][0], s[k16][1]);
            int pk1 = cvt_pk_bf16(s[k16][2], s[k16][3]);
            int pbase = 8 * k16 + 2 * lg;
            pw[lr * 32 + ((pbase + 0) ^ pswz)] = pk0;
            pw[lr * 32 + ((pbase + 1) ^ pswz)] = pk1;
        }
        bf16x8 pa0 = *(const bf16x8*)&pw[lr * 32 + ((4 * lg) ^ pswz)];
        bf16x8 pa1 = *(const bf16x8*)&pw[lr * 32 + ((16 + 4 * lg) ^ pswz)];

        __builtin_amdgcn_s_setprio(1);
#pragma unroll
        for (int vt = 0; vt < 4; vt++) {
            int dr = vt * 16 + lr;
            bf16x8 vf0 = *(const bf16x8*)&Vlds[cur][dr * 64 + ((0 + lg) ^ (dr & 7)) * 8];
            bf16x8 vf1 = *(const bf16x8*)&Vlds[cur][dr * 64 + ((4 + lg) ^ (dr & 7)) * 8];
            acc[vt] = __builtin_amdgcn_mfma_f32_16x16x32_bf16(pa0, vf0, acc[vt], 0, 0, 0);
            acc[vt] = __builtin_amdgcn_mfma_f32_16x16x32_bf16(pa1, vf1, acc[vt], 0, 0, 0);
        }
        __builtin_amdgcn_s_setprio(0);

        asm volatile("s_waitcnt vmcnt(0)" ::: "memory");
        __syncthreads();
    }

    float inv[4];
#pragma unroll
    for (int j = 0; j < 4; j++) inv[j] = 1.0f / __shfl(l_i, 4 * lg + j);
#pragma unroll
    for (int vt = 0; vt < 4; vt++) {
#pragma unroll
        for (int j = 0; j < 4; j++) {
            int qrow = qt * 64 + w * 16 + lg * 4 + j;
            if (qrow < SEQ) {
                AO[((size_t)(b * SEQ + qrow)) * DIM + h * HD64 + vt * 16 + lr] =
                    f2bf_rne(acc[vt][j] * inv[j]);
            }
        }
    }
}

extern "C" void kernel_launch(void* const* d_in, const int* in_sizes, int n_in,
                              void* d_out, int out_size, void* d_ws, size_t ws_size,
                              hipStream_t stream) {
    const float* x     = (const float*)d_in[0];
    const float* fcos  = (const float*)d_in[1];
    const float* fsin  = (const float*)d_in[2];
    const float* wqkv  = (const float*)d_in[3];
    const float* wproj = (const float*)d_in[4];
    const float* bproj = (const float*)d_in[5];
    float* out = (float*)d_out;

    char* ws = (char*)d_ws;
    size_t off = 0;
    auto salloc = [&](size_t bytes) { void* p = ws + off; off += (bytes + 255) & ~(size_t)255; return p; };
    short* xb     = (short*)salloc((size_t)M_ROWS * DIM * 2);
    short* wqkvb  = (short*)salloc((size_t)2304 * DIM * 2);
    short* wprojb = (short*)salloc((size_t)DIM * DIM * 2);
    short* Qb     = (short*)salloc((size_t)192 * SEQ * HD64 * 2);
    short* Kb     = (short*)salloc((size_t)192 * SEQ * HD64 * 2);
    short* VTb    = (short*)salloc((size_t)192 * HD64 * NPAD * 2);
    short* AO     = (short*)salloc((size_t)M_ROWS * DIM * 2);

    {
        int na4 = M_ROWS * DIM / 4;
        int nb4 = 2304 * DIM / 4;
        int nc4 = DIM * DIM / 4;
        int tot = na4 + nb4 + nc4;
        f2bf3_kernel<<<(tot + 255) / 256, 256, 0, stream>>>(x, xb, na4, wqkv, wqkvb, nb4, wproj, wprojb, nc4);
    }

    qkv_gemm_kernel<<<129 * 18, 256, 0, stream>>>(xb, wqkvb, fcos, fsin, Qb, Kb, VTb);
    attn_kernel<<<17 * 192, 256, 0, stream>>>(Qb, Kb, VTb, AO);
    proj_gemm_kernel<<<129 * 6, 256, 0, stream>>>(AO, wprojb, bproj, out);
}

// Round 11
// 340.348 us; speedup vs baseline: 1.4980x; 1.4980x over previous
//
#include <hip/hip_runtime.h>
#include <stdint.h>

#define NH 12
#define HD64 64
#define SEQ 1025
#define M_ROWS (16 * SEQ)   // 16400
#define DIM 768
#define NPAD 1088           // V^T row padding
#define KB 24               // K blocks of 32
#define BPAD 1088           // rows per batch, padded (17*64) for AOpk tiling

typedef __attribute__((ext_vector_type(8))) short bf16x8;
typedef __attribute__((ext_vector_type(4))) float f32x4;
typedef __attribute__((ext_vector_type(4))) short s16x4;

__device__ __forceinline__ short f2bf_rne(float f) {
    union { float f; uint32_t u; } c; c.f = f;
    uint32_t u = c.u + 0x7fffu + ((c.u >> 16) & 1u);
    return (short)(u >> 16);
}

__device__ __forceinline__ int cvt_pk_bf16(float lo, float hi) {
    int r;
    asm("v_cvt_pk_bf16_f32 %0, %1, %2" : "=v"(r) : "v"(lo), "v"(hi));
    return r;
}

__device__ __forceinline__ void gload_lds16(const void* g, void* l) {
    __builtin_amdgcn_global_load_lds(
        (const __attribute__((address_space(1))) void*)g,
        (__attribute__((address_space(3))) void*)l, 16, 0, 0);
}

// T1: XCD-chunked bijective swizzle (m204).
__device__ __forceinline__ int xcd_chunk_swizzle(int orig, int nwg) {
    int q = nwg >> 3, r = nwg & 7;
    int xcd = orig & 7, i = orig >> 3;
    int start = (xcd < r) ? xcd * (q + 1) : r * (q + 1) + (xcd - r) * q;
    return start + i;
}

// -------- pack fp32 matrices into bf16 MFMA-fragment order ----------
// dst[((r16*KB + kb)*64 + lane)*8 + 0..7] =
//   bf16(src[r16*16 + (lane&15)][kb*32 + (lane>>4)*8 + 0..7])
// A wave's fragment load becomes one contiguous 1KB global_load_dwordx4.
__global__ void pack_kernel(const float* __restrict__ x, short* __restrict__ Apk,
                            const float* __restrict__ wqkv, short* __restrict__ Wqpk,
                            const float* __restrict__ wproj, short* __restrict__ Wppk) {
    const int NA = 1025 * KB * 64, NB = 144 * KB * 64, NC = 48 * KB * 64;
    int id = blockIdx.x * 256 + threadIdx.x;
    const float* src; short* dst; int idx;
    if (id < NA) { src = x; dst = Apk; idx = id; }
    else if (id < NA + NB) { src = wqkv; dst = Wqpk; idx = id - NA; }
    else if (id < NA + NB + NC) { src = wproj; dst = Wppk; idx = id - NA - NB; }
    else return;
    int l = idx & 63, t = idx >> 6;
    int kb = t % KB, r16 = t / KB;
    int row = r16 * 16 + (l & 15);
    int col = kb * 32 + ((l >> 4) << 3);
    const float* p = src + (size_t)row * DIM + col;
    f32x4 f0 = *(const f32x4*)p;
    f32x4 f1 = *(const f32x4*)(p + 4);
    bf16x8 o;
    o[0] = f2bf_rne(f0[0]); o[1] = f2bf_rne(f0[1]); o[2] = f2bf_rne(f0[2]); o[3] = f2bf_rne(f0[3]);
    o[4] = f2bf_rne(f1[0]); o[5] = f2bf_rne(f1[1]); o[6] = f2bf_rne(f1[2]); o[7] = f2bf_rne(f1[3]);
    *(bf16x8*)(dst + (size_t)idx * 8) = o;
}

// ============ packed-direct GEMM core: no LDS, no barriers =============
// 4 waves (2x2), wave-tile 64x64, block 128x128. Fragments loaded straight
// from packed global: 8 coalesced 1KB loads + 16 MFMA per K-step, fully
// unrolled. TLP (no-LDS occupancy) + compiler pipelining hide L2 latency.

// ---------------- QKV GEMM + RoPE epilogue ----------------
__global__ __launch_bounds__(256) void qkv_gemm_kernel(
    const short* __restrict__ Apk, const short* __restrict__ Wqpk,
    const float* __restrict__ fcos, const float* __restrict__ fsin,
    short* __restrict__ Qb, short* __restrict__ Kb, short* __restrict__ VTb)
{
    const int tid = threadIdx.x;
    const int lane = tid & 63, w = tid >> 6;
    const int wm = w >> 1, wn = w & 1;
    const int lr = lane & 15, lg = lane >> 4;
    const int tile = xcd_chunk_swizzle(blockIdx.x, 129 * 18);
    const int mt = tile / 18, nt = tile - (tile / 18) * 18;

    const short* pA[4];
    const short* pB[4];
#pragma unroll
    for (int mi = 0; mi < 4; mi++) {
        int r16 = mt * 8 + wm * 4 + mi;
        if (r16 > 1024) r16 = 1024;                 // clamp last tile
        pA[mi] = Apk + (size_t)r16 * (KB * 512) + lane * 8;
    }
#pragma unroll
    for (int ni = 0; ni < 4; ni++) {
        int e16 = nt * 8 + wn * 4 + ni;             // < 144
        pB[ni] = Wqpk + (size_t)e16 * (KB * 512) + lane * 8;
    }

    f32x4 acc[4][4];
#pragma unroll
    for (int i = 0; i < 4; i++)
#pragma unroll
        for (int j = 0; j < 4; j++) acc[i][j] = (f32x4)0.0f;

#pragma unroll
    for (int kb = 0; kb < KB; ++kb) {
        bf16x8 af[4], bfr[4];
#pragma unroll
        for (int mi = 0; mi < 4; mi++)
            af[mi] = *(const bf16x8*)(pA[mi] + kb * 512);
#pragma unroll
        for (int ni = 0; ni < 4; ni++)
            bfr[ni] = *(const bf16x8*)(pB[ni] + kb * 512);
#pragma unroll
        for (int mi = 0; mi < 4; mi++)
#pragma unroll
            for (int ni = 0; ni < 4; ni++)
                acc[mi][ni] = __builtin_amdgcn_mfma_f32_16x16x32_bf16(af[mi], bfr[ni], acc[mi][ni], 0, 0, 0);
    }

    // epilogue: wave-uniform (qkv, h); RoPE pairs are adjacent cols = lane^1
    const int ebase = nt * 128 + wn * 64;
    const int qkvi = ebase / DIM;
    const int h = (ebase - qkvi * DIM) >> 6;
    const float qscale = (qkvi == 0) ? 0.180336881f : 1.0f;   // 1/8 * log2(e)
#pragma unroll
    for (int mi = 0; mi < 4; mi++) {
        int mbase = mt * 128 + wm * 64 + mi * 16 + lg * 4;
#pragma unroll
        for (int j = 0; j < 4; j++) {
            int m = mbase + j;
            bool valid = (m < M_ROWS);
            int mm = valid ? m : 0;
            int b = mm / SEQ;
            int n = mm - b * SEQ;
            size_t bh = (size_t)b * NH + h;
#pragma unroll
            for (int ni = 0; ni < 4; ni++) {
                int d = ni * 16 + lr;
                float v = acc[mi][ni][j];
                float vo = __shfl_xor(v, 1);
                float outv = v;
                if (qkvi < 2 && n > 0) {
                    float cs = fcos[(n - 1) * 32 + ni * 8 + (lr >> 1)];
                    float sn = fsin[(n - 1) * 32 + ni * 8 + (lr >> 1)];
                    outv = (d & 1) ? (vo * sn + v * cs) : (v * cs - vo * sn);
                }
                outv *= qscale;
                if (valid) {
                    short bv = f2bf_rne(outv);
                    if (qkvi == 0)      Qb[(bh * SEQ + n) * HD64 + d] = bv;
                    else if (qkvi == 1) Kb[(bh * SEQ + n) * HD64 + d] = bv;
                    else                VTb[(bh * HD64 + d) * NPAD + n] = bv;
                }
            }
        }
    }
}

// ---------------- output projection GEMM + bias (packed-direct) ----------------
// A = AOpk (batch rows padded to 1088 -> M' = 17408 = 136*128 exact).
__global__ __launch_bounds__(256) void proj_gemm_kernel(
    const short* __restrict__ AOpk, const short* __restrict__ Wppk,
    const float* __restrict__ bias, float* __restrict__ out)
{
    const int tid = threadIdx.x;
    const int lane = tid & 63, w = tid >> 6;
    const int wm = w >> 1, wn = w & 1;
    const int lr = lane & 15, lg = lane >> 4;
    const int tile = xcd_chunk_swizzle(blockIdx.x, 136 * 6);
    const int mt = tile / 6, nt = tile - (tile / 6) * 6;

    const short* pA[4];
    const short* pB[4];
#pragma unroll
    for (int mi = 0; mi < 4; mi++) {
        int r16 = mt * 8 + wm * 4 + mi;             // < 1088 exact
        pA[mi] = AOpk + (size_t)r16 * (KB * 512) + lane * 8;
    }
#pragma unroll
    for (int ni = 0; ni < 4; ni++) {
        int e16 = nt * 8 + wn * 4 + ni;             // < 48
        pB[ni] = Wppk + (size_t)e16 * (KB * 512) + lane * 8;
    }

    f32x4 acc[4][4];
#pragma unroll
    for (int i = 0; i < 4; i++)
#pragma unroll
        for (int j = 0; j < 4; j++) acc[i][j] = (f32x4)0.0f;

#pragma unroll
    for (int kb = 0; kb < KB; ++kb) {
        bf16x8 af[4], bfr[4];
#pragma unroll
        for (int mi = 0; mi < 4; mi++)
            af[mi] = *(const bf16x8*)(pA[mi] + kb * 512);
#pragma unroll
        for (int ni = 0; ni < 4; ni++)
            bfr[ni] = *(const bf16x8*)(pB[ni] + kb * 512);
#pragma unroll
        for (int mi = 0; mi < 4; mi++)
#pragma unroll
            for (int ni = 0; ni < 4; ni++)
                acc[mi][ni] = __builtin_amdgcn_mfma_f32_16x16x32_bf16(af[mi], bfr[ni], acc[mi][ni], 0, 0, 0);
    }

#pragma unroll
    for (int ni = 0; ni < 4; ni++) {
        int e = nt * 128 + wn * 64 + ni * 16 + lr;
        float bv = bias[e];
#pragma unroll
        for (int mi = 0; mi < 4; mi++) {
#pragma unroll
            for (int j = 0; j < 4; j++) {
                int mp = mt * 128 + wm * 64 + mi * 16 + lg * 4 + j;   // padded row
                int b = mp / BPAD;
                int q = mp - b * BPAD;
                if (q < SEQ) out[((size_t)b * SEQ + q) * DIM + e] = acc[mi][ni][j] + bv;
            }
        }
    }
}

// ---------------- flash attention ----------------
// (swapped QK^T, in-register softmax, dbuf K/V, T13, T5) + packed AOpk epilogue
__global__ __launch_bounds__(256) void attn_kernel(
    const short* __restrict__ Qb, const short* __restrict__ Kb,
    const short* __restrict__ VTb, short* __restrict__ AOpk)
{
    __shared__ short Klds[2][64 * 64];
    __shared__ short Vlds[2][64 * 64];
    __shared__ int Plds[4][16 * 32];
    const int tid = threadIdx.x;
    const int lane = tid & 63, w = tid >> 6;
    const int lr = lane & 15, lg = lane >> 4;
    const int tile = xcd_chunk_swizzle(blockIdx.x, 17 * 192);
    const int bh = tile / 17, qt = tile - (tile / 17) * 17;
    const int b = bh / NH, h = bh - b * NH;

    const short* Qp = Qb + (size_t)bh * SEQ * HD64;
    const short* Kp = Kb + (size_t)bh * SEQ * HD64;
    const short* Vp = VTb + (size_t)bh * HD64 * NPAD;

    int qr = qt * 64 + w * 16 + lr; if (qr > SEQ - 1) qr = SEQ - 1;
    bf16x8 qf0 = *(const bf16x8*)&Qp[(size_t)qr * HD64 + 0 + lg * 8];
    bf16x8 qf1 = *(const bf16x8*)&Qp[(size_t)qr * HD64 + 32 + lg * 8];

    float m_i = -1e30f, l_i = 0.f;
    f32x4 acc[4];
#pragma unroll
    for (int vt = 0; vt < 4; vt++) acc[vt] = (f32x4)0.0f;

    int* pw = &Plds[w][0];
    const int pswz = (lr & 3) << 3;

    auto stageKV = [&](int buf, int t) {
        int k0 = t * 64;
#pragma unroll
        for (int i = 0; i < 2; i++) {
            int c = i * 256 + tid;
            int row = c >> 3, ccd = c & 7;
            int cl = ccd ^ (row & 7);
            int krow = k0 + row; if (krow > SEQ - 1) krow = SEQ - 1;
            gload_lds16(Kp + (size_t)krow * HD64 + cl * 8, &Klds[buf][c * 8]);
            gload_lds16(Vp + (size_t)row * NPAD + k0 + cl * 8, &Vlds[buf][c * 8]);
        }
    };

    stageKV(0, 0);
    asm volatile("s_waitcnt vmcnt(0)" ::: "memory");
    __syncthreads();

    for (int t = 0; t < 17; ++t) {
        int cur = t & 1;
        if (t < 16) stageKV(cur ^ 1, t + 1);

        f32x4 s[4];
        __builtin_amdgcn_s_setprio(1);
#pragma unroll
        for (int k16 = 0; k16 < 4; k16++) {
            int krow = k16 * 16 + lr;
            bf16x8 kf0 = *(const bf16x8*)&Klds[cur][krow * 64 + ((0 + lg) ^ (krow & 7)) * 8];
            bf16x8 kf1 = *(const bf16x8*)&Klds[cur][krow * 64 + ((4 + lg) ^ (krow & 7)) * 8];
            f32x4 d = (f32x4)0.0f;
            d = __builtin_amdgcn_mfma_f32_16x16x32_bf16(kf0, qf0, d, 0, 0, 0);
            d = __builtin_amdgcn_mfma_f32_16x16x32_bf16(kf1, qf1, d, 0, 0, 0);
            s[k16] = d;
        }
        __builtin_amdgcn_s_setprio(0);
        if (t == 16) {
            s[0][0] = (lg == 0) ? s[0][0] : -1e30f;
            s[0][1] = -1e30f; s[0][2] = -1e30f; s[0][3] = -1e30f;
#pragma unroll
            for (int k16 = 1; k16 < 4; k16++) { s[k16][0] = -1e30f; s[k16][1] = -1e30f; s[k16][2] = -1e30f; s[k16][3] = -1e30f; }
        }

        float a0 = fmaxf(s[0][0], s[0][1]), a1 = fmaxf(s[0][2], s[0][3]);
        float a2 = fmaxf(s[1][0], s[1][1]), a3 = fmaxf(s[1][2], s[1][3]);
        float a4 = fmaxf(s[2][0], s[2][1]), a5 = fmaxf(s[2][2], s[2][3]);
        float a6 = fmaxf(s[3][0], s[3][1]), a7 = fmaxf(s[3][2], s[3][3]);
        float b0 = fmaxf(fmaxf(a0, a1), fmaxf(a2, a3));
        float b1 = fmaxf(fmaxf(a4, a5), fmaxf(a6, a7));
        float pmax = fmaxf(b0, b1);
        pmax = fmaxf(pmax, __shfl_xor(pmax, 16));
        pmax = fmaxf(pmax, __shfl_xor(pmax, 32));

        if (__any(pmax > m_i + 11.54f)) {
            float mnew = fmaxf(m_i, pmax);
            float sc = exp2f(m_i - mnew);
            m_i = mnew;
            l_i *= sc;
#pragma unroll
            for (int j = 0; j < 4; j++) {
                float scj = __shfl(sc, 4 * lg + j);
#pragma unroll
                for (int vt = 0; vt < 4; vt++) acc[vt][j] *= scj;
            }
        }

#pragma unroll
        for (int k16 = 0; k16 < 4; k16++) {
#pragma unroll
            for (int j = 0; j < 4; j++) s[k16][j] = exp2f(s[k16][j] - m_i);
        }
        float r0 = (s[0][0] + s[0][1]) + (s[0][2] + s[0][3]);
        float r1 = (s[1][0] + s[1][1]) + (s[1][2] + s[1][3]);
        float r2 = (s[2][0] + s[2][1]) + (s[2][2] + s[2][3]);
        float r3 = (s[3][0] + s[3][1]) + (s[3][2] + s[3][3]);
        float rowsum = (r0 + r1) + (r2 + r3);
        rowsum += __shfl_xor(rowsum, 16);
        rowsum += __shfl_xor(rowsum, 32);
        l_i += rowsum;

#pragma unroll
        for (int k16 = 0; k16 < 4; k16++) {
            int pk0 = cvt_pk_bf16(s[k16][0], s[k16][1]);
            int pk1 = cvt_pk_bf16(s[k16][2], s[k16][3]);
            int pbase = 8 * k16 + 2 * lg;
            pw[lr * 32 + ((pbase + 0) ^ pswz)] = pk0;
            pw[lr * 32 + ((pbase + 1) ^ pswz)] = pk1;
        }
        bf16x8 pa0 = *(const bf16x8*)&pw[lr * 32 + ((4 * lg) ^ pswz)];
        bf16x8 pa1 = *(const bf16x8*)&pw[lr * 32 + ((16 + 4 * lg) ^ pswz)];

        __builtin_amdgcn_s_setprio(1);
#pragma unroll
        for (int vt = 0; vt < 4; vt++) {
            int dr = vt * 16 + lr;
            bf16x8 vf0 = *(const bf16x8*)&Vlds[cur][dr * 64 + ((0 + lg) ^ (dr & 7)) * 8];
            bf16x8 vf1 = *(const bf16x8*)&Vlds[cur][dr * 64 + ((4 + lg) ^ (dr & 7)) * 8];
            acc[vt] = __builtin_amdgcn_mfma_f32_16x16x32_bf16(pa0, vf0, acc[vt], 0, 0, 0);
            acc[vt] = __builtin_amdgcn_mfma_f32_16x16x32_bf16(pa1, vf1, acc[vt], 0, 0, 0);
        }
        __builtin_amdgcn_s_setprio(0);

        asm volatile("s_waitcnt vmcnt(0)" ::: "memory");
        __syncthreads();
    }

    // ---- epilogue: write AOpk in MFMA-fragment order via per-wave LDS transpose
    float inv[4];
#pragma unroll
    for (int j = 0; j < 4; j++) inv[j] = 1.0f / __shfl(l_i, 4 * lg + j);

    short* sw = (short*)&Plds[w][0];    // 16 rows x 64 cols bf16, XOR-swizzled 8-col groups
#pragma unroll
    for (int vt = 0; vt < 4; vt++) {
#pragma unroll
        for (int j = 0; j < 4; j++) {
            int row = lg * 4 + j;
            int col = vt * 16 + lr;
            int g = (col >> 3) ^ (row & 7);
            sw[row * 64 + g * 8 + (col & 7)] = f2bf_rne(acc[vt][j] * inv[j]);
        }
    }
    const int r16p = b * 68 + qt * 4 + w;          // batch-padded (1088-row) tile index
    const int rrow = lane & 15;
#pragma unroll
    for (int q2 = 0; q2 < 2; q2++) {
        int g = q2 * 4 + (lane >> 4);
        bf16x8 frag = *(const bf16x8*)&sw[rrow * 64 + (g ^ (rrow & 7)) * 8];
        int kb = h * 2 + q2;
        *(bf16x8*)(AOpk + ((size_t)r16p * KB + kb) * 512 + lane * 8) = frag;
    }
}

extern "C" void kernel_launch(void* const* d_in, const int* in_sizes, int n_in,
                              void* d_out, int out_size, void* d_ws, size_t ws_size,
                              hipStream_t stream) {
    const float* x     = (const float*)d_in[0];
    const float* fcos  = (const float*)d_in[1];
    const float* fsin  = (const float*)d_in[2];
    const float* wqkv  = (const float*)d_in[3];
    const float* wproj = (const float*)d_in[4];
    const float* bproj = (const float*)d_in[5];
    float* out = (float*)d_out;

    char* ws = (char*)d_ws;
    size_t off = 0;
    auto salloc = [&](size_t bytes) { void* p = ws + off; off += (bytes + 255) & ~(size_t)255; return p; };
    short* Apk   = (short*)salloc((size_t)1025 * KB * 512 * 2);
    short* Wqpk  = (short*)salloc((size_t)144 * KB * 512 * 2);
    short* Wppk  = (short*)salloc((size_t)48 * KB * 512 * 2);
    short* Qb    = (short*)salloc((size_t)192 * SEQ * HD64 * 2);
    short* Kb    = (short*)salloc((size_t)192 * SEQ * HD64 * 2);
    short* VTb   = (short*)salloc((size_t)192 * HD64 * NPAD * 2);
    short* AOpk  = (short*)salloc((size_t)1088 * KB * 512 * 2);

    {
        int tot = (1025 + 144 + 48) * KB * 64;
        pack_kernel<<<(tot + 255) / 256, 256, 0, stream>>>(x, Apk, wqkv, Wqpk, wproj, Wppk);
    }

    qkv_gemm_kernel<<<129 * 18, 256, 0, stream>>>(Apk, Wqpk, fcos, fsin, Qb, Kb, VTb);
    attn_kernel<<<17 * 192, 256, 0, stream>>>(Qb, Kb, VTb, AOpk);
    proj_gemm_kernel<<<136 * 6, 256, 0, stream>>>(AOpk, Wppk, bproj, out);
}